// Round 6
// baseline (334.209 us; speedup 1.0000x reference)
//
#include <hip/hip_runtime.h>
#include <math.h>

// ---------------------------------------------------------------------------
// 2-layer GCN:  out = GCNConv(relu(GCNConv(x, W1, b1)), W2, b2)
// Factorization: g = (x@W) * dinv[row];  agg[d] = g[d] + sum_{s in in(d)} g[s];
//                out[d] = agg[d]*dinv[d] + b   (dinv = rsqrt(indeg+1))
//
// R1-R5: bucket sort -> LDS sort -> bf16 G rows -> dwordx4 gathers (342us).
// R6: slice-lockstep + LDS float atomics: FETCH 162->61MB (locality PROVEN)
//   but float LDS atomics = CAS path, 1366us. REVERTED.
// R7: (range,node) bins, serial per-edge chains: FETCH 63MB kept, 168us
//   (latency chains + 196-block grid). REVERTED.
// R8: (node,range) CSR, streaming grid: execution recovered (58.5us) but
//   FETCH back to 162MB -- no phase coherence without co-residency. 337us.
// R9: gemm restructure + prep deletion: only -5us. Lesson: stop blind prep
//   work; aggregate (116us, FETCH 2x162MB vs proven 61MB floor) is the one
//   measured, understood target.
// R10: slice-phased aggregate satisfying ALL of R6-R8's lessons:
//   - register acc (no LDS atomics): 8-lane group OWNS 2 dst nodes
//   - branchless value-masked batched gathers, 4 chains in flight
//   - NSLICE=4 (3.3MB G-slices fit 4MB/XCD L2), bins avg 8 edges
//   - co-resident grid (1563 blocks x 256thr), __syncthreads per slice,
//     cross-block coherence statistical (R7 proved this suffices: 63MB)
//   csr key = (node,slice); cnt4[node] = 4x u16 slice counts.
// R11: R10 bench died to container infra (no counters, no fail verdict);
//   source re-audited for barrier-divergence/OOB/hang -- clean. Resubmit.
// ---------------------------------------------------------------------------

#define BKT_SHIFT 9               // 512 nodes per bucket
#define BKT_NODES 512
#define NBSH      256             // >= bucket count (196)
#define CHUNK     8192            // edges per bucket_bin block
#define MAXB      20480           // fixed per-bucket region (mean ~16.3k, 32 sigma)

typedef unsigned short ushort_t;

static __device__ __forceinline__ unsigned short f2bf(float f) {
    unsigned u = __float_as_uint(f);
    unsigned r = (u + 0x7FFFu + ((u >> 16) & 1u)) >> 16;   // RNE
    return (unsigned short)r;
}
static __device__ __forceinline__ float bf_lo(unsigned u) {
    return __uint_as_float(u << 16);
}
static __device__ __forceinline__ float bf_hi(unsigned u) {
    return __uint_as_float(u & 0xFFFF0000u);
}

struct ushort4_t { unsigned short x, y, z, w; };

// Phase A: bin edges into fixed-stride bucket regions (pairs[b*MAXB ...]).
// Packed pair: (dst&511)<<17 | src  (src < 2^17). bcur = per-bucket cursor.
__global__ __launch_bounds__(256) void bucket_bin(const int* __restrict__ src,
                                                  const int* __restrict__ dst,
                                                  int* __restrict__ bcur,
                                                  unsigned* __restrict__ pairs,
                                                  int E, int NB) {
    __shared__ unsigned stag[CHUNK];   // 32KB
    __shared__ int hist[NBSH];
    __shared__ int lofs[NBSH];
    __shared__ int lcur[NBSH];
    __shared__ int gbase[NBSH];
    const int t  = threadIdx.x;
    const int e0 = blockIdx.x * CHUNK;
    const int n  = min(CHUNK, E - e0);

    for (int i = t; i < NBSH; i += 256) hist[i] = 0;
    __syncthreads();
    for (int i = t; i < n; i += 256) atomicAdd(&hist[dst[e0 + i] >> BKT_SHIFT], 1);
    __syncthreads();
    int v = hist[t];
    lofs[t] = v;
    __syncthreads();
    for (int d = 1; d < 256; d <<= 1) {
        int u = (t >= d) ? lofs[t - d] : 0;
        __syncthreads();
        lofs[t] += u;
        __syncthreads();
    }
    if (t < NB) {
        lcur[t]  = lofs[t] - v;
        gbase[t] = (v > 0) ? t * MAXB + atomicAdd(&bcur[t], v) : 0;
    }
    __syncthreads();
    for (int i = t; i < n; i += 256) {
        int d = dst[e0 + i];
        int s = src[e0 + i];
        int b = d >> BKT_SHIFT;
        int p = atomicAdd(&lcur[b], 1);
        stag[p] = ((unsigned)(d & (BKT_NODES - 1)) << 17) | (unsigned)s;
    }
    __syncthreads();
    // copy-out: wave-per-bucket (parallel across the 4 waves, 64-lane runs)
    const int wv = t >> 6, ln = t & 63;
    for (int b = wv; b < NB; b += 4) {
        int cb = hist[b];
        if (cb == 0) continue;
        int lo = lofs[b] - cb;
        int gb = gbase[b];
        int lim = min(cb, (b + 1) * MAXB - gb);   // overflow clamp (never in practice)
        for (int i = ln; i < lim; i += 64) pairs[gb + i] = stag[lo + i];
    }
}

// Phase B: per-bucket 2048-bin counting sort, key = (dst_node<<2)|src_slice.
// slice(src) = (src*41)>>20: 4 balanced ~25.6k-node slices (3.3MB of G each).
// Emits csr (src values, node-major slice-minor), offs, cnt4 (4x u16), dinv.
__global__ __launch_bounds__(1024) void csr_sort3(const unsigned* __restrict__ pairs,
                                                  const int* __restrict__ bcur,
                                                  unsigned* __restrict__ csr,
                                                  int* __restrict__ offs,
                                                  uint2* __restrict__ cnt4,
                                                  float* __restrict__ dinv, int N) {
    extern __shared__ unsigned st[];   // MAXB entries (80KB)
    __shared__ int h[2048];            // 8KB: counts -> exclusive cursors
    __shared__ int sc[1024];           // 4KB scan temp
    const int b    = blockIdx.x;
    const int t    = threadIdx.x;
    const int n0   = b << BKT_SHIFT;
    const int base = b * MAXB;
    const int ne   = min(bcur[b], MAXB);

    h[t] = 0; h[t + 1024] = 0;
    __syncthreads();
    for (int i = t; i < ne; i += 1024) {
        unsigned p  = pairs[base + i];
        unsigned sv = p & 0x1FFFFu;
        int key = (int)(((p >> 17) << 2) | ((sv * 41u) >> 20));
        atomicAdd(&h[key], 1);
    }
    __syncthreads();
    // per-node slice counts -> cnt4/dinv (raw counts, before cursor overwrite)
    if (t < BKT_NODES) {
        int node = n0 + t;
        if (node < N) {
            int a = h[4 * t], bb = h[4 * t + 1], c = h[4 * t + 2], d = h[4 * t + 3];
            cnt4[node] = make_uint2((unsigned)a | ((unsigned)bb << 16),
                                    (unsigned)c | ((unsigned)d << 16));
            dinv[node] = rsqrtf((float)(a + bb + c + d + 1));
        }
    }
    // exclusive scan over 2048 bins: 2 bins/thread + 1024-wide scan
    int v0 = h[2 * t], v1 = h[2 * t + 1];
    int lsum = v0 + v1;
    sc[t] = lsum;
    __syncthreads();
    for (int d = 1; d < 1024; d <<= 1) {
        int u = (t >= d) ? sc[t - d] : 0;
        __syncthreads();
        sc[t] += u;
        __syncthreads();
    }
    int run = sc[t] - lsum;
    h[2 * t]     = run;        // cursor = exclusive bin start
    h[2 * t + 1] = run + v0;
    __syncthreads();
    if (t < BKT_NODES) {
        int node = n0 + t;
        if (node < N) offs[node] = base + h[4 * t];
    }
    __syncthreads();
    for (int i = t; i < ne; i += 1024) {
        unsigned p  = pairs[base + i];
        unsigned sv = p & 0x1FFFFu;
        int key = (int)(((p >> 17) << 2) | ((sv * 41u) >> 20));
        int pos = atomicAdd(&h[key], 1);
        st[pos] = sv;
    }
    __syncthreads();
    for (int i = t; i < ne; i += 1024) csr[base + i] = st[i];
}

// G[row] = bf16( (X[row] @ W) * dinv[row] ).  X:[N,K] f32, W:[K,64], G:[N,64] bf16.
template <int K>
__global__ __launch_bounds__(256) void gemm_scale(const float* __restrict__ X,
                                                  const float* __restrict__ W,
                                                  const float* __restrict__ dinv,
                                                  ushort_t* __restrict__ G, int N) {
    __shared__ float Ws[K * 64];
    const int t  = threadIdx.x;
    const int r0 = blockIdx.x * 128;

    for (int i = t; i < K * 16; i += 256)
        ((float4*)Ws)[i] = ((const float4*)W)[i];

    const int cg = (t & 15) * 4;           // column group
    const int rb = r0 + (t >> 4) * 8;      // first of this thread's 8 rows

    float acc[8][4];
#pragma unroll
    for (int j = 0; j < 8; ++j) {
        acc[j][0] = 0.f; acc[j][1] = 0.f; acc[j][2] = 0.f; acc[j][3] = 0.f;
    }
    __syncthreads();

    const bool full = (rb + 8 <= N);
    for (int k = 0; k < K; k += 4) {
        float4 xr[8];
        if (full) {
#pragma unroll
            for (int j = 0; j < 8; ++j)
                xr[j] = *(const float4*)(X + (size_t)(rb + j) * K + k);
        } else {
#pragma unroll
            for (int j = 0; j < 8; ++j)
                xr[j] = (rb + j < N) ? *(const float4*)(X + (size_t)(rb + j) * K + k)
                                     : make_float4(0.f, 0.f, 0.f, 0.f);
        }
#pragma unroll
        for (int kk = 0; kk < 4; ++kk) {
            float4 w = *(const float4*)&Ws[(k + kk) * 64 + cg];
#pragma unroll
            for (int j = 0; j < 8; ++j) {
                float xv = (&xr[j].x)[kk];
                acc[j][0] = fmaf(xv, w.x, acc[j][0]);
                acc[j][1] = fmaf(xv, w.y, acc[j][1]);
                acc[j][2] = fmaf(xv, w.z, acc[j][2]);
                acc[j][3] = fmaf(xv, w.w, acc[j][3]);
            }
        }
    }

#pragma unroll
    for (int j = 0; j < 8; ++j) {
        int row = rb + j;
        if (row < N) {
            float s = dinv[row];
            ushort4_t o = { f2bf(acc[j][0] * s), f2bf(acc[j][1] * s),
                            f2bf(acc[j][2] * s), f2bf(acc[j][3] * s) };
            *(ushort4_t*)(G + (size_t)row * 64 + cg) = o;
        }
    }
}

#define ACCA(v)                                           \
    acc0[0] += bf_lo((v).x); acc0[1] += bf_hi((v).x);     \
    acc0[2] += bf_lo((v).y); acc0[3] += bf_hi((v).y);     \
    acc0[4] += bf_lo((v).z); acc0[5] += bf_hi((v).z);     \
    acc0[6] += bf_lo((v).w); acc0[7] += bf_hi((v).w);
#define ACCB(v)                                           \
    acc1[0] += bf_lo((v).x); acc1[1] += bf_hi((v).x);     \
    acc1[2] += bf_lo((v).y); acc1[3] += bf_hi((v).y);     \
    acc1[4] += bf_lo((v).z); acc1[5] += bf_hi((v).z);     \
    acc1[6] += bf_lo((v).w); acc1[7] += bf_hi((v).w);

// Slice-phased aggregate: 8-lane group OWNS 2 dst nodes (register acc, no
// shuffles/atomics). 4 slice phases; all co-resident blocks sweep slice s
// together -> gather working set = one 3.3MB G-slice per XCD L2.
// Inner loop branchless: clamped-index csr loads + value masking, 4 chains.
__global__ __launch_bounds__(256) void aggregate7(const ushort_t* __restrict__ G,
                                                  const int* __restrict__ offs,
                                                  const uint2* __restrict__ cnt4,
                                                  const unsigned* __restrict__ csr,
                                                  const float* __restrict__ dinv,
                                                  const float* __restrict__ bias,
                                                  float* __restrict__ out, int N,
                                                  int do_relu) {
    const int t   = threadIdx.x;
    const int sub = t & 7;                       // 16B chunk of the 128B row
    const int gg  = t >> 3;                      // group id in block: 0..31
    const int nA  = blockIdx.x * 64 + gg * 2;    // group's two nodes
    const int nB  = nA + 1;

    const bool okA = (nA < N), okB = (nB < N);
    uint2 cA = okA ? cnt4[nA] : make_uint2(0u, 0u);
    uint2 cB = okB ? cnt4[nB] : make_uint2(0u, 0u);
    int posA = okA ? offs[nA] : 0;
    int posB = okB ? offs[nB] : 0;

    float acc0[8] = {0.f, 0.f, 0.f, 0.f, 0.f, 0.f, 0.f, 0.f};
    float acc1[8] = {0.f, 0.f, 0.f, 0.f, 0.f, 0.f, 0.f, 0.f};

#pragma unroll
    for (int s = 0; s < 4; ++s) {
        const int lenA = (int)((s == 0 ? cA.x : s == 1 ? cA.x >> 16
                              : s == 2 ? cA.y : cA.y >> 16) & 0xFFFFu);
        const int lenB = (int)((s == 0 ? cB.x : s == 1 ? cB.x >> 16
                              : s == 2 ? cB.y : cB.y >> 16) & 0xFFFFu);
        const int jm = max(lenA, lenB);
        for (int j = 0; j < jm; j += 2) {
            const int j1 = j + 1;
            const bool aA0 = j < lenA, aA1 = j1 < lenA;
            const bool aB0 = j < lenB, aB1 = j1 < lenB;
            unsigned sA0 = csr[posA + (aA0 ? j : 0)];
            unsigned sB0 = csr[posB + (aB0 ? j : 0)];
            unsigned sA1 = csr[posA + (aA1 ? j1 : 0)];
            unsigned sB1 = csr[posB + (aB1 ? j1 : 0)];
            uint4 vA0 = *(const uint4*)(G + ((size_t)sA0 << 6) + (sub << 3));
            uint4 vB0 = *(const uint4*)(G + ((size_t)sB0 << 6) + (sub << 3));
            uint4 vA1 = *(const uint4*)(G + ((size_t)sA1 << 6) + (sub << 3));
            uint4 vB1 = *(const uint4*)(G + ((size_t)sB1 << 6) + (sub << 3));
            unsigned mA0 = aA0 ? 0xFFFFFFFFu : 0u;
            unsigned mB0 = aB0 ? 0xFFFFFFFFu : 0u;
            unsigned mA1 = aA1 ? 0xFFFFFFFFu : 0u;
            unsigned mB1 = aB1 ? 0xFFFFFFFFu : 0u;
            vA0.x &= mA0; vA0.y &= mA0; vA0.z &= mA0; vA0.w &= mA0;
            vB0.x &= mB0; vB0.y &= mB0; vB0.z &= mB0; vB0.w &= mB0;
            vA1.x &= mA1; vA1.y &= mA1; vA1.z &= mA1; vA1.w &= mA1;
            vB1.x &= mB1; vB1.y &= mB1; vB1.z &= mB1; vB1.w &= mB1;
            ACCA(vA0); ACCB(vB0); ACCA(vA1); ACCB(vB1);
        }
        posA += lenA;
        posB += lenB;
        __syncthreads();   // slice phase boundary (block-level pacing)
    }

    // self-loop + epilogue; all 64 lanes store (each group its own nodes)
    float4 bl0 = *(const float4*)(bias + sub * 8);
    float4 bl1 = *(const float4*)(bias + sub * 8 + 4);
    if (okA) {
        uint4 v = *(const uint4*)(G + ((size_t)nA << 6) + (sub << 3));
        ACCA(v);
        float d = dinv[nA];
        float4 o0 = make_float4(fmaf(acc0[0], d, bl0.x), fmaf(acc0[1], d, bl0.y),
                                fmaf(acc0[2], d, bl0.z), fmaf(acc0[3], d, bl0.w));
        float4 o1 = make_float4(fmaf(acc0[4], d, bl1.x), fmaf(acc0[5], d, bl1.y),
                                fmaf(acc0[6], d, bl1.z), fmaf(acc0[7], d, bl1.w));
        if (do_relu) {
            o0.x = fmaxf(o0.x, 0.f); o0.y = fmaxf(o0.y, 0.f);
            o0.z = fmaxf(o0.z, 0.f); o0.w = fmaxf(o0.w, 0.f);
            o1.x = fmaxf(o1.x, 0.f); o1.y = fmaxf(o1.y, 0.f);
            o1.z = fmaxf(o1.z, 0.f); o1.w = fmaxf(o1.w, 0.f);
        }
        *(float4*)(out + (size_t)nA * 64 + sub * 8)     = o0;
        *(float4*)(out + (size_t)nA * 64 + sub * 8 + 4) = o1;
    }
    if (okB) {
        uint4 v = *(const uint4*)(G + ((size_t)nB << 6) + (sub << 3));
        ACCB(v);
        float d = dinv[nB];
        float4 o0 = make_float4(fmaf(acc1[0], d, bl0.x), fmaf(acc1[1], d, bl0.y),
                                fmaf(acc1[2], d, bl0.z), fmaf(acc1[3], d, bl0.w));
        float4 o1 = make_float4(fmaf(acc1[4], d, bl1.x), fmaf(acc1[5], d, bl1.y),
                                fmaf(acc1[6], d, bl1.z), fmaf(acc1[7], d, bl1.w));
        if (do_relu) {
            o0.x = fmaxf(o0.x, 0.f); o0.y = fmaxf(o0.y, 0.f);
            o0.z = fmaxf(o0.z, 0.f); o0.w = fmaxf(o0.w, 0.f);
            o1.x = fmaxf(o1.x, 0.f); o1.y = fmaxf(o1.y, 0.f);
            o1.z = fmaxf(o1.z, 0.f); o1.w = fmaxf(o1.w, 0.f);
        }
        *(float4*)(out + (size_t)nB * 64 + sub * 8)     = o0;
        *(float4*)(out + (size_t)nB * 64 + sub * 8 + 4) = o1;
    }
}

extern "C" void kernel_launch(void* const* d_in, const int* in_sizes, int n_in,
                              void* d_out, int out_size, void* d_ws, size_t ws_size,
                              hipStream_t stream) {
    const float* x  = (const float*)d_in[0];
    const int*   ei = (const int*)d_in[1];
    const float* W1 = (const float*)d_in[2];
    const float* b1 = (const float*)d_in[3];
    const float* W2 = (const float*)d_in[4];
    const float* b2 = (const float*)d_in[5];
    float* out = (float*)d_out;

    const int IN_CH = 128;
    const int N = in_sizes[0] / IN_CH;   // 100000
    const int E = in_sizes[1] / 2;       // 3200000
    const int* src = ei;
    const int* dst = ei + E;
    const int NB = (N + BKT_NODES - 1) >> BKT_SHIFT;  // 196

    char* ws = (char*)d_ws;
    size_t off = 0;
    auto take = [&](size_t bytes) -> char* {
        char* p = ws + off;
        off += (bytes + 255) & ~(size_t)255;
        return p;
    };
    float*    dinv  = (float*)take((size_t)N * 4);
    int*      offs  = (int*)take((size_t)N * 4);
    uint2*    cnt4  = (uint2*)take((size_t)N * 8);
    int*      bcur  = (int*)take(NBSH * 4);
    unsigned* csr   = (unsigned*)take(((size_t)NB * MAXB + 64) * 4);  // +pad
    ushort_t* g     = (ushort_t*)take((size_t)N * 64 * 2);            // 12.8MB
    float*    a1    = (float*)take((size_t)N * 64 * 4);               // 25.6MB
    unsigned* pairs = (unsigned*)a1;   // NB*MAXB*4 <= N*64*4; dead before agg1 writes a1

    const int nbC = (E + CHUNK - 1) / CHUNK;
    const int nbA = (N + 63) / 64;     // aggregate7 blocks (64 nodes each)

    hipMemsetAsync(bcur, 0, NBSH * 4, stream);
    bucket_bin<<<nbC, 256, 0, stream>>>(src, dst, bcur, pairs, E, NB);
    csr_sort3<<<NB, 1024, MAXB * 4, stream>>>(pairs, bcur, csr, offs, cnt4, dinv, N);

    // layer 1
    gemm_scale<128><<<(N + 127) / 128, 256, 0, stream>>>(x, W1, dinv, g, N);
    aggregate7<<<nbA, 256, 0, stream>>>(g, offs, cnt4, csr, dinv, b1, a1, N, 1);
    // layer 2
    gemm_scale<64><<<(N + 127) / 128, 256, 0, stream>>>(a1, W2, dinv, g, N);
    aggregate7<<<nbA, 256, 0, stream>>>(g, offs, cnt4, csr, dinv, b2, out, N, 0);
}